// Round 1
// baseline (491.835 us; speedup 1.0000x reference)
//
#include <hip/hip_runtime.h>
#include <cstdint>
#include <cstddef>

// ---------------- problem constants ----------------
#define BATCH   2
#define LSEQ    1024
#define DMODEL  1024
#define DINNER  2048
#define DSTATE  16
#define DTRANK  64
#define TTOT    2048   // BATCH*LSEQ

typedef __attribute__((ext_vector_type(8))) __bf16 bf16x8;
typedef __attribute__((ext_vector_type(4))) float f32x4;
typedef __attribute__((ext_vector_type(4))) unsigned int u32x4;

__device__ __forceinline__ unsigned short f2bf(float f) {
  union { float f; unsigned u; } v; v.f = f;
  unsigned r = v.u + 0x7FFFu + ((v.u >> 16) & 1u);
  return (unsigned short)(r >> 16);
}

__device__ __forceinline__ void gload16(const void* g, void* l) {
  __builtin_amdgcn_global_load_lds((__attribute__((address_space(1))) void*)g,
                                   (__attribute__((address_space(3))) void*)l, 16, 0, 0);
}

// ---------------- cast kernels ----------------
__global__ __launch_bounds__(256) void cast_bf_kernel(const float* __restrict__ in,
                                                      unsigned short* __restrict__ out, int n) {
  int i = blockIdx.x * 256 + threadIdx.x;
  if (i < n) out[i] = f2bf(in[i]);
}

// W_x (96,2048) -> padded (128,2048) bf16, rows 96..127 = 0
__global__ __launch_bounds__(256) void cast_wx_kernel(const float* __restrict__ in,
                                                      unsigned short* __restrict__ out) {
  int i = blockIdx.x * 256 + threadIdx.x;  // 128*2048
  int r = i >> 11, c = i & 2047;
  out[i] = (r < 96) ? f2bf(in[r * 2048 + c]) : (unsigned short)0;
}

// dt = x_dbl[:, 0:64] -> bf16
__global__ __launch_bounds__(256) void extract_dt_kernel(const float* __restrict__ x_dbl,
                                                         unsigned short* __restrict__ dt_bf) {
  int i = blockIdx.x * 256 + threadIdx.x;  // 2048*64
  int t = i >> 6, r = i & 63;
  dt_bf[i] = f2bf(x_dbl[t * 128 + r]);
}

// ---------------- MFMA GEMM: C(MxN) f32 = A(MxK) bf16 * B(NxK)^T bf16 ----------------
// m97 structure: 128x128 tile, BK=32, 4 waves, global_load_lds width 16.
// Requires M%128==0, N%128==0, K%32==0.
__global__ __launch_bounds__(256) void gemm_bt(const unsigned short* __restrict__ A,
                                               const unsigned short* __restrict__ B,
                                               float* __restrict__ C, int M, int N, int K) {
  __shared__ __align__(16) unsigned short As[128 * 32];
  __shared__ __align__(16) unsigned short Bs[128 * 32];
  const int tid  = threadIdx.x;
  const int wave = tid >> 6;
  const int lane = tid & 63;
  const int bm = blockIdx.y, bn = blockIdx.x;
  const int wr = wave >> 1, wc = wave & 1;           // wave tile (64x64)
  const int r15 = lane & 15, kblk = lane >> 4;
  f32x4 acc[4][4] = {};

  const int c0 = tid;          // staging chunk ids (16B each), j=0
  const int c1 = tid + 256;    // j=1
  const size_t aoff0 = (size_t)(bm * 128 + (c0 >> 2)) * K + (size_t)(c0 & 3) * 8;
  const size_t aoff1 = (size_t)(bm * 128 + (c1 >> 2)) * K + (size_t)(c1 & 3) * 8;
  const size_t boff0 = (size_t)(bn * 128 + (c0 >> 2)) * K + (size_t)(c0 & 3) * 8;
  const size_t boff1 = (size_t)(bn * 128 + (c1 >> 2)) * K + (size_t)(c1 & 3) * 8;
  unsigned short* as0 = &As[(wave * 64) * 8];
  unsigned short* as1 = &As[(256 + wave * 64) * 8];
  unsigned short* bs0 = &Bs[(wave * 64) * 8];
  unsigned short* bs1 = &Bs[(256 + wave * 64) * 8];

  for (int k0 = 0; k0 < K; k0 += 32) {
    gload16(A + aoff0 + k0, as0);
    gload16(A + aoff1 + k0, as1);
    gload16(B + boff0 + k0, bs0);
    gload16(B + boff1 + k0, bs1);
    __syncthreads();  // drains vmcnt -> tile staged
    const u32x4* As4 = (const u32x4*)As;
    const u32x4* Bs4 = (const u32x4*)Bs;
    bf16x8 af[4], bfr[4];
#pragma unroll
    for (int m = 0; m < 4; ++m)
      af[m] = __builtin_bit_cast(bf16x8, As4[(wr * 64 + m * 16 + r15) * 4 + kblk]);
#pragma unroll
    for (int n = 0; n < 4; ++n)
      bfr[n] = __builtin_bit_cast(bf16x8, Bs4[(wc * 64 + n * 16 + r15) * 4 + kblk]);
#pragma unroll
    for (int m = 0; m < 4; ++m)
#pragma unroll
      for (int n = 0; n < 4; ++n)
        acc[m][n] = __builtin_amdgcn_mfma_f32_16x16x32_bf16(af[m], bfr[n], acc[m][n], 0, 0, 0);
    __syncthreads();
  }
  // C/D layout: col = lane&15, row = (lane>>4)*4 + reg   [measured m89]
  const int crow = bm * 128 + wr * 64 + (lane >> 4) * 4;
  const int ccol = bn * 128 + wc * 64 + r15;
#pragma unroll
  for (int m = 0; m < 4; ++m)
#pragma unroll
    for (int n = 0; n < 4; ++n)
#pragma unroll
      for (int r = 0; r < 4; ++r)
        C[(size_t)(crow + m * 16 + r) * N + (ccol + n * 16)] = acc[m][n][r];
}

// ---------------- depthwise causal conv (k=4) + SiLU ----------------
__global__ __launch_bounds__(256) void conv_silu_kernel(const float* __restrict__ xz,
                                                        const float* __restrict__ cw,
                                                        const float* __restrict__ cb,
                                                        float* __restrict__ u,
                                                        unsigned short* __restrict__ u_bf) {
  int i = blockIdx.x * 256 + threadIdx.x;  // TTOT * DINNER
  int d = i & (DINNER - 1);
  int t = i >> 11;
  int l = t & (LSEQ - 1);
  const float* col = xz + (size_t)t * 4096 + d;   // u-part of xz: cols [0,2048)
  float acc = cb[d];
  float w0 = cw[d * 4 + 0], w1 = cw[d * 4 + 1], w2 = cw[d * 4 + 2], w3 = cw[d * 4 + 3];
  if (l >= 3) acc += w0 * col[-3 * 4096];
  if (l >= 2) acc += w1 * col[-2 * 4096];
  if (l >= 1) acc += w2 * col[-1 * 4096];
  acc += w3 * col[0];
  float s = acc / (1.f + __expf(-acc));           // silu
  u[i] = s;
  u_bf[i] = f2bf(s);
}

// ---------------- selective scan (fused gating), LDS-tiled over time ----------------
// 64 blocks x 256 thr. Block = (b, 64 channels). 4 lanes per channel (4 states each).
#define SCAN_TILE 16
__global__ __launch_bounds__(256) void scan_kernel(
    const float* __restrict__ delta_pre, const float* __restrict__ b_dt,
    const float* __restrict__ u, const float* __restrict__ xz,
    const float* __restrict__ x_dbl, const float* __restrict__ A_log,
    const float* __restrict__ Dp, unsigned short* __restrict__ y_bf) {
  __shared__ __align__(16) float smem[2][3584];  // per buf: dp[16][64] ut[16][64] zt[16][64] bc[16][32]
  const int tid  = threadIdx.x;
  const int wave = tid >> 6;
  const int lane = tid & 63; (void)lane;
  const int g  = tid & 3;          // state group (4 states each)
  const int dl = tid >> 2;         // 0..63 channel within block
  const int bb = blockIdx.x;       // 0..63
  const int b = bb >> 5;
  const int dbase = (bb & 31) * 64;
  const int d = dbase + dl;
  float An[4];
#pragma unroll
  for (int i = 0; i < 4; ++i) An[i] = -__expf(A_log[d * 16 + g * 4 + i]);
  const float bdt = b_dt[d];
  const float Dpd = Dp[d];
  float s0 = 0.f, s1 = 0.f, s2 = 0.f, s3 = 0.f;
  const int tb = b * LSEQ;

  auto stage = [&](int buf, int tile) {
    const int t0 = tb + tile * SCAN_TILE;
    float* sm = smem[buf];
    {
      int c = wave * 64 + (tid & 63);           // 0..255
      int r = c >> 4, w = c & 15;
      gload16(delta_pre + (size_t)(t0 + r) * 2048 + dbase + w * 4, sm + 0    + wave * 256);
      gload16(u         + (size_t)(t0 + r) * 2048 + dbase + w * 4, sm + 1024 + wave * 256);
      gload16(xz + (size_t)(t0 + r) * 4096 + 2048 + dbase + w * 4, sm + 2048 + wave * 256);
    }
    if (wave < 2) {
      int c = wave * 64 + (tid & 63);           // 0..127
      int r = c >> 3, w = c & 7;
      gload16(x_dbl + (size_t)(t0 + r) * 128 + 64 + w * 4, sm + 3072 + wave * 256);
    }
  };

  stage(0, 0);
  for (int tile = 0; tile < LSEQ / SCAN_TILE; ++tile) {
    __syncthreads();                      // staged tile ready; prev reads done
    if (tile + 1 < LSEQ / SCAN_TILE) stage((tile + 1) & 1, tile + 1);
    const float* sm = smem[tile & 1];
#pragma unroll
    for (int r = 0; r < SCAN_TILE; ++r) {
      const int t = tb + tile * SCAN_TILE + r;
      float dp = sm[r * 64 + dl];
      float ut = sm[1024 + r * 64 + dl];
      float zt = sm[2048 + r * 64 + dl];
      const float4 Bp = *(const float4*)(sm + 3072 + r * 32 + g * 4);
      const float4 Cp = *(const float4*)(sm + 3072 + r * 32 + 16 + g * 4);
      float xs = dp + bdt;
      float delta = (xs > 15.f) ? xs : __logf(1.f + __expf(xs));   // softplus
      float dBu = delta * ut;
      float y;
      float e0 = __expf(delta * An[0]); s0 = fmaf(e0, s0, dBu * Bp.x); y = s0 * Cp.x;
      float e1 = __expf(delta * An[1]); s1 = fmaf(e1, s1, dBu * Bp.y); y = fmaf(s1, Cp.y, y);
      float e2 = __expf(delta * An[2]); s2 = fmaf(e2, s2, dBu * Bp.z); y = fmaf(s2, Cp.z, y);
      float e3 = __expf(delta * An[3]); s3 = fmaf(e3, s3, dBu * Bp.w); y = fmaf(s3, Cp.w, y);
      y += __shfl_xor(y, 1);
      y += __shfl_xor(y, 2);
      if (g == 0) {
        float yf = (y + ut * Dpd) * (zt / (1.f + __expf(-zt)));    // + u*D, * silu(z)
        y_bf[(size_t)t * 2048 + d] = f2bf(yf);
      }
    }
  }
}

// ---------------- launch ----------------
extern "C" void kernel_launch(void* const* d_in, const int* in_sizes, int n_in,
                              void* d_out, int out_size, void* d_ws, size_t ws_size,
                              hipStream_t stream) {
  (void)in_sizes; (void)n_in; (void)out_size; (void)ws_size;
  const float* x      = (const float*)d_in[0];
  const float* W_in   = (const float*)d_in[1];
  const float* conv_w = (const float*)d_in[2];
  const float* conv_b = (const float*)d_in[3];
  const float* W_x    = (const float*)d_in[4];
  const float* W_dt   = (const float*)d_in[5];
  const float* b_dt   = (const float*)d_in[6];
  const float* A_log  = (const float*)d_in[7];
  const float* Dp     = (const float*)d_in[8];
  const float* W_out  = (const float*)d_in[9];
  float* out = (float*)d_out;

  char* ws = (char*)d_ws;
  size_t off = 0;
  auto alloc = [&](size_t bytes) { void* p = ws + off; off += (bytes + 255) & ~(size_t)255; return p; };
  unsigned short* x_bf    = (unsigned short*)alloc((size_t)TTOT * 1024 * 2);
  unsigned short* Win_bf  = (unsigned short*)alloc((size_t)4096 * 1024 * 2);
  unsigned short* Wout_bf = (unsigned short*)alloc((size_t)1024 * 2048 * 2);
  unsigned short* Wx_bf   = (unsigned short*)alloc((size_t)128 * 2048 * 2);
  unsigned short* Wdt_bf  = (unsigned short*)alloc((size_t)2048 * 64 * 2);
  float* xz        = (float*)alloc((size_t)TTOT * 4096 * 4);
  float* u         = (float*)alloc((size_t)TTOT * 2048 * 4);
  unsigned short* u_bf = (unsigned short*)alloc((size_t)TTOT * 2048 * 2);
  float* x_dbl     = (float*)alloc((size_t)TTOT * 128 * 4);
  unsigned short* dt_bf = (unsigned short*)alloc((size_t)TTOT * 64 * 2);
  float* delta_pre = (float*)alloc((size_t)TTOT * 2048 * 4);
  unsigned short* y_bf  = (unsigned short*)alloc((size_t)TTOT * 2048 * 2);

  // casts
  cast_bf_kernel<<<(TTOT * 1024) / 256, 256, 0, stream>>>(x, x_bf, TTOT * 1024);
  cast_bf_kernel<<<(4096 * 1024) / 256, 256, 0, stream>>>(W_in, Win_bf, 4096 * 1024);
  cast_bf_kernel<<<(1024 * 2048) / 256, 256, 0, stream>>>(W_out, Wout_bf, 1024 * 2048);
  cast_wx_kernel<<<(128 * 2048) / 256, 256, 0, stream>>>(W_x, Wx_bf);
  cast_bf_kernel<<<(2048 * 64) / 256, 256, 0, stream>>>(W_dt, Wdt_bf, 2048 * 64);

  // in_proj: xz = x @ W_in^T   (2048 x 4096, K=1024)
  gemm_bt<<<dim3(4096 / 128, TTOT / 128), 256, 0, stream>>>(x_bf, Win_bf, xz, TTOT, 4096, 1024);
  // conv + silu -> u (f32 + bf16)
  conv_silu_kernel<<<(TTOT * DINNER) / 256, 256, 0, stream>>>(xz, conv_w, conv_b, u, u_bf);
  // x_dbl = u @ W_x^T  (2048 x 128(pad), K=2048)
  gemm_bt<<<dim3(128 / 128, TTOT / 128), 256, 0, stream>>>(u_bf, Wx_bf, x_dbl, TTOT, 128, 2048);
  // dt cast
  extract_dt_kernel<<<(TTOT * 64) / 256, 256, 0, stream>>>(x_dbl, dt_bf);
  // delta_pre = dt @ W_dt^T  (2048 x 2048, K=64)
  gemm_bt<<<dim3(2048 / 128, TTOT / 128), 256, 0, stream>>>(dt_bf, Wdt_bf, delta_pre, TTOT, 2048, 64);
  // selective scan + gating -> y_bf
  scan_kernel<<<64, 256, 0, stream>>>(delta_pre, b_dt, u, xz, x_dbl, A_log, Dp, y_bf);
  // out = y @ W_out^T  (2048 x 1024, K=2048)
  gemm_bt<<<dim3(1024 / 128, TTOT / 128), 256, 0, stream>>>(y_bf, Wout_bf, out, TTOT, 1024, 2048);
}

// Round 2
// 233.598 us; speedup vs baseline: 2.1055x; 2.1055x over previous
//
#include <hip/hip_runtime.h>
#include <cstdint>
#include <cstddef>

// ---------------- problem constants ----------------
#define BATCH   2
#define LSEQ    1024
#define DMODEL  1024
#define DINNER  2048
#define DSTATE  16
#define DTRANK  64
#define TTOT    2048   // BATCH*LSEQ
#define NC      16     // scan chunks
#define LC      64     // steps per chunk

typedef __attribute__((ext_vector_type(8))) __bf16 bf16x8;
typedef __attribute__((ext_vector_type(4))) float f32x4;
typedef __attribute__((ext_vector_type(4))) unsigned int u32x4;

__device__ __forceinline__ unsigned short f2bf(float f) {
  union { float f; unsigned u; } v; v.f = f;
  unsigned r = v.u + 0x7FFFu + ((v.u >> 16) & 1u);
  return (unsigned short)(r >> 16);
}

__device__ __forceinline__ void gload16(const void* g, void* l) {
  __builtin_amdgcn_global_load_lds((__attribute__((address_space(1))) void*)g,
                                   (__attribute__((address_space(3))) void*)l, 16, 0, 0);
}

// ---------------- cast kernels ----------------
__global__ __launch_bounds__(256) void cast_bf_kernel(const float* __restrict__ in,
                                                      unsigned short* __restrict__ out, int n) {
  int i = blockIdx.x * 256 + threadIdx.x;
  if (i < n) out[i] = f2bf(in[i]);
}

// W_x (96,2048) -> padded (128,2048) bf16, rows 96..127 = 0
__global__ __launch_bounds__(256) void cast_wx_kernel(const float* __restrict__ in,
                                                      unsigned short* __restrict__ out) {
  int i = blockIdx.x * 256 + threadIdx.x;  // 128*2048
  int r = i >> 11, c = i & 2047;
  out[i] = (r < 96) ? f2bf(in[r * 2048 + c]) : (unsigned short)0;
}

// dt = x_dbl[:, 0:64] -> bf16
__global__ __launch_bounds__(256) void extract_dt_kernel(const float* __restrict__ x_dbl,
                                                         unsigned short* __restrict__ dt_bf) {
  int i = blockIdx.x * 256 + threadIdx.x;  // 2048*64
  int t = i >> 6, r = i & 63;
  dt_bf[i] = f2bf(x_dbl[t * 128 + r]);
}

// ---------------- MFMA GEMM: C(MxN) f32 = A(MxK) bf16 * B(NxK)^T bf16 ----------------
__global__ __launch_bounds__(256) void gemm_bt(const unsigned short* __restrict__ A,
                                               const unsigned short* __restrict__ B,
                                               float* __restrict__ C, int M, int N, int K) {
  __shared__ __align__(16) unsigned short As[128 * 32];
  __shared__ __align__(16) unsigned short Bs[128 * 32];
  const int tid  = threadIdx.x;
  const int wave = tid >> 6;
  const int lane = tid & 63;
  const int bm = blockIdx.y, bn = blockIdx.x;
  const int wr = wave >> 1, wc = wave & 1;           // wave tile (64x64)
  const int r15 = lane & 15, kblk = lane >> 4;
  f32x4 acc[4][4] = {};

  const int c0 = tid;          // staging chunk ids (16B each), j=0
  const int c1 = tid + 256;    // j=1
  const size_t aoff0 = (size_t)(bm * 128 + (c0 >> 2)) * K + (size_t)(c0 & 3) * 8;
  const size_t aoff1 = (size_t)(bm * 128 + (c1 >> 2)) * K + (size_t)(c1 & 3) * 8;
  const size_t boff0 = (size_t)(bn * 128 + (c0 >> 2)) * K + (size_t)(c0 & 3) * 8;
  const size_t boff1 = (size_t)(bn * 128 + (c1 >> 2)) * K + (size_t)(c1 & 3) * 8;
  unsigned short* as0 = &As[(wave * 64) * 8];
  unsigned short* as1 = &As[(256 + wave * 64) * 8];
  unsigned short* bs0 = &Bs[(wave * 64) * 8];
  unsigned short* bs1 = &Bs[(256 + wave * 64) * 8];

  for (int k0 = 0; k0 < K; k0 += 32) {
    gload16(A + aoff0 + k0, as0);
    gload16(A + aoff1 + k0, as1);
    gload16(B + boff0 + k0, bs0);
    gload16(B + boff1 + k0, bs1);
    __syncthreads();  // drains vmcnt -> tile staged
    const u32x4* As4 = (const u32x4*)As;
    const u32x4* Bs4 = (const u32x4*)Bs;
    bf16x8 af[4], bfr[4];
#pragma unroll
    for (int m = 0; m < 4; ++m)
      af[m] = __builtin_bit_cast(bf16x8, As4[(wr * 64 + m * 16 + r15) * 4 + kblk]);
#pragma unroll
    for (int n = 0; n < 4; ++n)
      bfr[n] = __builtin_bit_cast(bf16x8, Bs4[(wc * 64 + n * 16 + r15) * 4 + kblk]);
#pragma unroll
    for (int m = 0; m < 4; ++m)
#pragma unroll
      for (int n = 0; n < 4; ++n)
        acc[m][n] = __builtin_amdgcn_mfma_f32_16x16x32_bf16(af[m], bfr[n], acc[m][n], 0, 0, 0);
    __syncthreads();
  }
  // C/D layout: col = lane&15, row = (lane>>4)*4 + reg   [measured m89]
  const int crow = bm * 128 + wr * 64 + (lane >> 4) * 4;
  const int ccol = bn * 128 + wc * 64 + r15;
#pragma unroll
  for (int m = 0; m < 4; ++m)
#pragma unroll
    for (int n = 0; n < 4; ++n)
#pragma unroll
      for (int r = 0; r < 4; ++r)
        C[(size_t)(crow + m * 16 + r) * N + (ccol + n * 16)] = acc[m][n][r];
}

// ---------------- depthwise causal conv (k=4) + SiLU ----------------
__global__ __launch_bounds__(256) void conv_silu_kernel(const float* __restrict__ xz,
                                                        const float* __restrict__ cw,
                                                        const float* __restrict__ cb,
                                                        float* __restrict__ u,
                                                        unsigned short* __restrict__ u_bf) {
  int i = blockIdx.x * 256 + threadIdx.x;  // TTOT * DINNER
  int d = i & (DINNER - 1);
  int t = i >> 11;
  int l = t & (LSEQ - 1);
  const float* col = xz + (size_t)t * 4096 + d;   // u-part of xz: cols [0,2048)
  float acc = cb[d];
  float w0 = cw[d * 4 + 0], w1 = cw[d * 4 + 1], w2 = cw[d * 4 + 2], w3 = cw[d * 4 + 3];
  if (l >= 3) acc += w0 * col[-3 * 4096];
  if (l >= 2) acc += w1 * col[-2 * 4096];
  if (l >= 1) acc += w2 * col[-1 * 4096];
  acc += w3 * col[0];
  float s = acc / (1.f + __expf(-acc));           // silu
  u[i] = s;
  u_bf[i] = f2bf(s);
}

// ---------------- chunked selective scan ----------------
// Chain: s_t = exp(delta_t*A)*s_{t-1} + delta_t*u_t*B_t, per (b,d,n).
// PASS 0: per chunk, compute P = exp(A*sum(delta)) and S = chunk-local state (zero init).
// mid:    sequential over NC=16 chunk summaries per chain -> s_init per chunk.
// PASS 1: replay chunk from s_init, emit y_t = <s_t, C_t>, + u*D, * silu(z), -> bf16.
// Block = (b, chunk, 64 channels); 4 lanes/channel x 4 states/lane. Grid 1024 blocks.
template<int PASS>
__global__ __launch_bounds__(256) void scan_pass_kernel(
    const float* __restrict__ delta_pre, const float* __restrict__ b_dt,
    const float* __restrict__ u, const float* __restrict__ xz,
    const float* __restrict__ x_dbl, const float* __restrict__ A_log,
    const float* __restrict__ Dp, float* __restrict__ Pc, float* __restrict__ Sc,
    const float* __restrict__ s_init, unsigned short* __restrict__ y_bf) {
  __shared__ __align__(16) float smem[2][3584];  // dp[16][64] ut[16][64] zt[16][64] bc[16][32]
  const int tid  = threadIdx.x;
  const int wave = tid >> 6;
  const int g  = tid & 3;          // state group (4 states each)
  const int dl = tid >> 2;         // channel within block
  const int dbase = blockIdx.x * 64;
  const int ch = blockIdx.y;       // chunk
  const int b  = blockIdx.z;
  const int d = dbase + dl;
  float An[4];
#pragma unroll
  for (int i = 0; i < 4; ++i) An[i] = -__expf(A_log[d * 16 + g * 4 + i]);
  const float bdt = b_dt[d];
  const float Dpd = (PASS == 1) ? Dp[d] : 0.f;
  const size_t chainbase = ((size_t)(b * NC + ch) * DINNER + d) * 16 + g * 4;
  float s0 = 0.f, s1 = 0.f, s2 = 0.f, s3 = 0.f;
  float sumdelta = 0.f;
  if (PASS == 1) {
    const float4 si = *(const float4*)(s_init + chainbase);
    s0 = si.x; s1 = si.y; s2 = si.z; s3 = si.w;
  }
  const int tb = b * LSEQ + ch * LC;

  auto stage = [&](int buf, int tile) {
    const int t0 = tb + tile * 16;
    float* sm = smem[buf];
    {
      int r = tid >> 4, w = tid & 15;
      gload16(delta_pre + (size_t)(t0 + r) * 2048 + dbase + w * 4, sm + 0    + wave * 256);
      gload16(u         + (size_t)(t0 + r) * 2048 + dbase + w * 4, sm + 1024 + wave * 256);
      if (PASS == 1)
        gload16(xz + (size_t)(t0 + r) * 4096 + 2048 + dbase + w * 4, sm + 2048 + wave * 256);
    }
    if (wave < 2) {
      int c2 = wave * 64 + (tid & 63);
      int r2 = c2 >> 3, w2 = c2 & 7;
      gload16(x_dbl + (size_t)(t0 + r2) * 128 + 64 + w2 * 4, sm + 3072 + wave * 256);
    }
  };

  stage(0, 0);
  for (int tile = 0; tile < LC / 16; ++tile) {
    __syncthreads();                      // staged tile ready; prev reads done
    if (tile + 1 < LC / 16) stage((tile + 1) & 1, tile + 1);
    const float* sm = smem[tile & 1];
#pragma unroll
    for (int r = 0; r < 16; ++r) {
      float dp = sm[r * 64 + dl];
      float ut = sm[1024 + r * 64 + dl];
      const float4 Bp = *(const float4*)(sm + 3072 + r * 32 + g * 4);
      float xs = dp + bdt;
      float delta = (xs > 15.f) ? xs : __logf(1.f + __expf(xs));   // softplus
      if (PASS == 0) sumdelta += delta;
      float dBu = delta * ut;
      float e0 = __expf(delta * An[0]); s0 = fmaf(e0, s0, dBu * Bp.x);
      float e1 = __expf(delta * An[1]); s1 = fmaf(e1, s1, dBu * Bp.y);
      float e2 = __expf(delta * An[2]); s2 = fmaf(e2, s2, dBu * Bp.z);
      float e3 = __expf(delta * An[3]); s3 = fmaf(e3, s3, dBu * Bp.w);
      if (PASS == 1) {
        const float4 Cp = *(const float4*)(sm + 3072 + r * 32 + 16 + g * 4);
        float zt = sm[2048 + r * 64 + dl];
        float y = s0 * Cp.x;
        y = fmaf(s1, Cp.y, y);
        y = fmaf(s2, Cp.z, y);
        y = fmaf(s3, Cp.w, y);
        y += __shfl_xor(y, 1);
        y += __shfl_xor(y, 2);
        if (g == 0) {
          const int t = tb + tile * 16 + r;
          float yf = (y + ut * Dpd) * (zt / (1.f + __expf(-zt)));  // + u*D, * silu(z)
          y_bf[(size_t)t * 2048 + d] = f2bf(yf);
        }
      }
    }
  }
  if (PASS == 0) {
    float4 P, S;
    P.x = __expf(An[0] * sumdelta);
    P.y = __expf(An[1] * sumdelta);
    P.z = __expf(An[2] * sumdelta);
    P.w = __expf(An[3] * sumdelta);
    S.x = s0; S.y = s1; S.z = s2; S.w = s3;
    *(float4*)(Pc + chainbase) = P;
    *(float4*)(Sc + chainbase) = S;
  }
}

// sequential composition over the NC chunk summaries, one thread per chain
__global__ __launch_bounds__(256) void scan_mid_kernel(const float* __restrict__ Pc,
                                                       const float* __restrict__ Sc,
                                                       float* __restrict__ s_init) {
  int i = blockIdx.x * 256 + threadIdx.x;   // 65536 chains: (b*DINNER+d)*16+n
  int b = i >> 15;
  int rest = i & 32767;
  const size_t stride = (size_t)DINNER * 16;
  size_t base = (size_t)b * NC * stride + rest;
  float s = 0.f;
#pragma unroll
  for (int c = 0; c < NC; ++c) {
    s_init[base + c * stride] = s;
    s = fmaf(Pc[base + c * stride], s, Sc[base + c * stride]);
  }
}

// ---------------- launch ----------------
extern "C" void kernel_launch(void* const* d_in, const int* in_sizes, int n_in,
                              void* d_out, int out_size, void* d_ws, size_t ws_size,
                              hipStream_t stream) {
  (void)in_sizes; (void)n_in; (void)out_size; (void)ws_size;
  const float* x      = (const float*)d_in[0];
  const float* W_in   = (const float*)d_in[1];
  const float* conv_w = (const float*)d_in[2];
  const float* conv_b = (const float*)d_in[3];
  const float* W_x    = (const float*)d_in[4];
  const float* W_dt   = (const float*)d_in[5];
  const float* b_dt   = (const float*)d_in[6];
  const float* A_log  = (const float*)d_in[7];
  const float* Dp     = (const float*)d_in[8];
  const float* W_out  = (const float*)d_in[9];
  float* out = (float*)d_out;

  char* ws = (char*)d_ws;
  size_t off = 0;
  auto alloc = [&](size_t bytes) { void* p = ws + off; off += (bytes + 255) & ~(size_t)255; return p; };
  unsigned short* x_bf    = (unsigned short*)alloc((size_t)TTOT * 1024 * 2);
  unsigned short* Win_bf  = (unsigned short*)alloc((size_t)4096 * 1024 * 2);
  unsigned short* Wout_bf = (unsigned short*)alloc((size_t)1024 * 2048 * 2);
  unsigned short* Wx_bf   = (unsigned short*)alloc((size_t)128 * 2048 * 2);
  unsigned short* Wdt_bf  = (unsigned short*)alloc((size_t)2048 * 64 * 2);
  float* xz        = (float*)alloc((size_t)TTOT * 4096 * 4);
  float* u         = (float*)alloc((size_t)TTOT * 2048 * 4);
  unsigned short* u_bf = (unsigned short*)alloc((size_t)TTOT * 2048 * 2);
  float* x_dbl     = (float*)alloc((size_t)TTOT * 128 * 4);
  unsigned short* dt_bf = (unsigned short*)alloc((size_t)TTOT * 64 * 2);
  float* delta_pre = (float*)alloc((size_t)TTOT * 2048 * 4);
  unsigned short* y_bf  = (unsigned short*)alloc((size_t)TTOT * 2048 * 2);
  float* Pc     = (float*)alloc((size_t)BATCH * NC * DINNER * 16 * 4);
  float* Sc     = (float*)alloc((size_t)BATCH * NC * DINNER * 16 * 4);
  float* s_init = (float*)alloc((size_t)BATCH * NC * DINNER * 16 * 4);

  // casts
  cast_bf_kernel<<<(TTOT * 1024) / 256, 256, 0, stream>>>(x, x_bf, TTOT * 1024);
  cast_bf_kernel<<<(4096 * 1024) / 256, 256, 0, stream>>>(W_in, Win_bf, 4096 * 1024);
  cast_bf_kernel<<<(1024 * 2048) / 256, 256, 0, stream>>>(W_out, Wout_bf, 1024 * 2048);
  cast_wx_kernel<<<(128 * 2048) / 256, 256, 0, stream>>>(W_x, Wx_bf);
  cast_bf_kernel<<<(2048 * 64) / 256, 256, 0, stream>>>(W_dt, Wdt_bf, 2048 * 64);

  // in_proj: xz = x @ W_in^T   (2048 x 4096, K=1024)
  gemm_bt<<<dim3(4096 / 128, TTOT / 128), 256, 0, stream>>>(x_bf, Win_bf, xz, TTOT, 4096, 1024);
  // conv + silu -> u (f32 + bf16)
  conv_silu_kernel<<<(TTOT * DINNER) / 256, 256, 0, stream>>>(xz, conv_w, conv_b, u, u_bf);
  // x_dbl = u @ W_x^T  (2048 x 128(pad), K=2048)
  gemm_bt<<<dim3(128 / 128, TTOT / 128), 256, 0, stream>>>(u_bf, Wx_bf, x_dbl, TTOT, 128, 2048);
  // dt cast
  extract_dt_kernel<<<(TTOT * 64) / 256, 256, 0, stream>>>(x_dbl, dt_bf);
  // delta_pre = dt @ W_dt^T  (2048 x 2048, K=64)
  gemm_bt<<<dim3(2048 / 128, TTOT / 128), 256, 0, stream>>>(dt_bf, Wdt_bf, delta_pre, TTOT, 2048, 64);
  // chunked selective scan
  scan_pass_kernel<0><<<dim3(DINNER / 64, NC, BATCH), 256, 0, stream>>>(
      delta_pre, b_dt, u, xz, x_dbl, A_log, Dp, Pc, Sc, nullptr, nullptr);
  scan_mid_kernel<<<(BATCH * DINNER * 16) / 256, 256, 0, stream>>>(Pc, Sc, s_init);
  scan_pass_kernel<1><<<dim3(DINNER / 64, NC, BATCH), 256, 0, stream>>>(
      delta_pre, b_dt, u, xz, x_dbl, A_log, Dp, nullptr, nullptr, s_init, y_bf);
  // out = y @ W_out^T  (2048 x 1024, K=2048)
  gemm_bt<<<dim3(1024 / 128, TTOT / 128), 256, 0, stream>>>(y_bf, Wout_bf, out, TTOT, 1024, 2048);
}

// Round 3
// 190.406 us; speedup vs baseline: 2.5831x; 1.2268x over previous
//
#include <hip/hip_runtime.h>
#include <cstdint>
#include <cstddef>

// ---------------- problem constants ----------------
#define BATCH   2
#define LSEQ    1024
#define DMODEL  1024
#define DINNER  2048
#define DSTATE  16
#define DTRANK  64
#define TTOT    2048   // BATCH*LSEQ
#define NC      16     // scan chunks
#define LC      64     // steps per chunk
#define KSPLIT  8      // x_dbl GEMM K-split

typedef __attribute__((ext_vector_type(8))) __bf16 bf16x8;
typedef __attribute__((ext_vector_type(4))) float f32x4;
typedef __attribute__((ext_vector_type(4))) unsigned int u32x4;
typedef __attribute__((ext_vector_type(4))) unsigned short u16x4;

__device__ __forceinline__ unsigned short f2bf(float f) {
  union { float f; unsigned u; } v; v.f = f;
  unsigned r = v.u + 0x7FFFu + ((v.u >> 16) & 1u);
  return (unsigned short)(r >> 16);
}

__device__ __forceinline__ void gload16(const void* g, void* l) {
  __builtin_amdgcn_global_load_lds((__attribute__((address_space(1))) void*)g,
                                   (__attribute__((address_space(3))) void*)l, 16, 0, 0);
}

// ---------------- fused cast kernel (all f32->bf16 inputs, 4 elems/thread) ----------------
#define N_X    (TTOT * 1024)
#define N_WIN  (4096 * 1024)
#define N_WOUT (1024 * 2048)
#define N_WDT  (2048 * 64)
#define N_WXP  (128 * 2048)
#define CAST_TOT (N_X + N_WIN + N_WOUT + N_WDT + N_WXP)

__global__ __launch_bounds__(256) void cast_all_kernel(
    const float* __restrict__ x, const float* __restrict__ W_in,
    const float* __restrict__ W_out, const float* __restrict__ W_dt,
    const float* __restrict__ W_x,
    unsigned short* __restrict__ x_bf, unsigned short* __restrict__ Win_bf,
    unsigned short* __restrict__ Wout_bf, unsigned short* __restrict__ Wdt_bf,
    unsigned short* __restrict__ Wx_bf) {
  const int idx = (blockIdx.x * 256 + threadIdx.x) * 4;
  float4 v;
  unsigned short* dst;
  if (idx < N_X) {
    v = *(const float4*)(x + idx); dst = x_bf + idx;
  } else if (idx < N_X + N_WIN) {
    int j = idx - N_X; v = *(const float4*)(W_in + j); dst = Win_bf + j;
  } else if (idx < N_X + N_WIN + N_WOUT) {
    int j = idx - (N_X + N_WIN); v = *(const float4*)(W_out + j); dst = Wout_bf + j;
  } else if (idx < N_X + N_WIN + N_WOUT + N_WDT) {
    int j = idx - (N_X + N_WIN + N_WOUT); v = *(const float4*)(W_dt + j); dst = Wdt_bf + j;
  } else {
    int j = idx - (N_X + N_WIN + N_WOUT + N_WDT);
    int r = j >> 11, c = j & 2047;
    if (r < 96) v = *(const float4*)(W_x + r * 2048 + c);
    else        v = make_float4(0.f, 0.f, 0.f, 0.f);
    dst = Wx_bf + j;
  }
  u16x4 o; o[0] = f2bf(v.x); o[1] = f2bf(v.y); o[2] = f2bf(v.z); o[3] = f2bf(v.w);
  *(u16x4*)dst = o;
}

// ---------------- MFMA GEMM: C(128-tile) f32 = A(MxK,lda) * B(NxK,ldb)^T ----------------
// m97 structure: 128x128 tile, BK=32, 4 waves, global_load_lds width 16.
// blockIdx.z = K-split slice: A/B advance kOff elements, C advances cOff elements.
__global__ __launch_bounds__(256) void gemm_bt(const unsigned short* __restrict__ A, int lda,
                                               const unsigned short* __restrict__ B, int ldb,
                                               float* __restrict__ C, int ldc,
                                               int K, int kOff, size_t cOff) {
  A += (size_t)blockIdx.z * kOff;
  B += (size_t)blockIdx.z * kOff;
  C += (size_t)blockIdx.z * cOff;
  __shared__ __align__(16) unsigned short As[128 * 32];
  __shared__ __align__(16) unsigned short Bs[128 * 32];
  const int tid  = threadIdx.x;
  const int wave = tid >> 6;
  const int lane = tid & 63;
  const int bm = blockIdx.y, bn = blockIdx.x;
  const int wr = wave >> 1, wc = wave & 1;           // wave tile (64x64)
  const int r15 = lane & 15, kblk = lane >> 4;
  f32x4 acc[4][4] = {};

  const int c0 = tid;          // staging chunk ids (16B each)
  const int c1 = tid + 256;
  const size_t aoff0 = (size_t)(bm * 128 + (c0 >> 2)) * lda + (size_t)(c0 & 3) * 8;
  const size_t aoff1 = (size_t)(bm * 128 + (c1 >> 2)) * lda + (size_t)(c1 & 3) * 8;
  const size_t boff0 = (size_t)(bn * 128 + (c0 >> 2)) * ldb + (size_t)(c0 & 3) * 8;
  const size_t boff1 = (size_t)(bn * 128 + (c1 >> 2)) * ldb + (size_t)(c1 & 3) * 8;
  unsigned short* as0 = &As[(wave * 64) * 8];
  unsigned short* as1 = &As[(256 + wave * 64) * 8];
  unsigned short* bs0 = &Bs[(wave * 64) * 8];
  unsigned short* bs1 = &Bs[(256 + wave * 64) * 8];

  for (int k0 = 0; k0 < K; k0 += 32) {
    gload16(A + aoff0 + k0, as0);
    gload16(A + aoff1 + k0, as1);
    gload16(B + boff0 + k0, bs0);
    gload16(B + boff1 + k0, bs1);
    __syncthreads();  // drains vmcnt -> tile staged
    const u32x4* As4 = (const u32x4*)As;
    const u32x4* Bs4 = (const u32x4*)Bs;
    bf16x8 af[4], bfr[4];
#pragma unroll
    for (int m = 0; m < 4; ++m)
      af[m] = __builtin_bit_cast(bf16x8, As4[(wr * 64 + m * 16 + r15) * 4 + kblk]);
#pragma unroll
    for (int n = 0; n < 4; ++n)
      bfr[n] = __builtin_bit_cast(bf16x8, Bs4[(wc * 64 + n * 16 + r15) * 4 + kblk]);
#pragma unroll
    for (int m = 0; m < 4; ++m)
#pragma unroll
      for (int n = 0; n < 4; ++n)
        acc[m][n] = __builtin_amdgcn_mfma_f32_16x16x32_bf16(af[m], bfr[n], acc[m][n], 0, 0, 0);
    __syncthreads();
  }
  // C/D layout: col = lane&15, row = (lane>>4)*4 + reg   [measured m89]
  const int crow = bm * 128 + wr * 64 + (lane >> 4) * 4;
  const int ccol = bn * 128 + wc * 64 + r15;
#pragma unroll
  for (int m = 0; m < 4; ++m)
#pragma unroll
    for (int n = 0; n < 4; ++n)
#pragma unroll
      for (int r = 0; r < 4; ++r)
        C[(size_t)(crow + m * 16 + r) * ldc + (ccol + n * 16)] = acc[m][n][r];
}

// ---------------- x_dbl split-K reduce (+ dt extraction) ----------------
__global__ __launch_bounds__(256) void reduce_xdbl_kernel(const float* __restrict__ part,
                                                          float* __restrict__ x_dbl,
                                                          unsigned short* __restrict__ dt_bf) {
  int i = blockIdx.x * 256 + threadIdx.x;   // 2048*128
  float s = 0.f;
#pragma unroll
  for (int k = 0; k < KSPLIT; ++k) s += part[(size_t)k * (2048 * 128) + i];
  x_dbl[i] = s;
  int col = i & 127, t = i >> 7;
  if (col < 64) dt_bf[t * 64 + col] = f2bf(s);
}

// ---------------- depthwise causal conv (k=4) + SiLU ----------------
__global__ __launch_bounds__(256) void conv_silu_kernel(const float* __restrict__ xz,
                                                        const float* __restrict__ cw,
                                                        const float* __restrict__ cb,
                                                        float* __restrict__ u,
                                                        unsigned short* __restrict__ u_bf) {
  int i = blockIdx.x * 256 + threadIdx.x;  // TTOT * DINNER
  int d = i & (DINNER - 1);
  int t = i >> 11;
  int l = t & (LSEQ - 1);
  const float* col = xz + (size_t)t * 4096 + d;   // u-part of xz: cols [0,2048)
  float acc = cb[d];
  float w0 = cw[d * 4 + 0], w1 = cw[d * 4 + 1], w2 = cw[d * 4 + 2], w3 = cw[d * 4 + 3];
  if (l >= 3) acc += w0 * col[-3 * 4096];
  if (l >= 2) acc += w1 * col[-2 * 4096];
  if (l >= 1) acc += w2 * col[-1 * 4096];
  acc += w3 * col[0];
  float s = acc / (1.f + __expf(-acc));           // silu
  u[i] = s;
  u_bf[i] = f2bf(s);
}

// ---------------- chunked selective scan ----------------
// PASS 0: per chunk, P = exp(A*sum(delta)), S = chunk-local state (zero init).
// mid:    sequential over NC chunk summaries per chain -> s_init per chunk.
// PASS 1: replay from s_init, emit y_t = <s_t,C_t> + u*D, * silu(z), -> bf16.
template<int PASS>
__global__ __launch_bounds__(256) void scan_pass_kernel(
    const float* __restrict__ delta_pre, const float* __restrict__ b_dt,
    const float* __restrict__ u, const float* __restrict__ xz,
    const float* __restrict__ x_dbl, const float* __restrict__ A_log,
    const float* __restrict__ Dp, float* __restrict__ Pc, float* __restrict__ Sc,
    const float* __restrict__ s_init, unsigned short* __restrict__ y_bf) {
  __shared__ __align__(16) float smem[2][3584];  // dp[16][64] ut[16][64] zt[16][64] bc[16][32]
  const int tid  = threadIdx.x;
  const int wave = tid >> 6;
  const int g  = tid & 3;          // state group (4 states each)
  const int dl = tid >> 2;         // channel within block
  const int dbase = blockIdx.x * 64;
  const int ch = blockIdx.y;       // chunk
  const int b  = blockIdx.z;
  const int d = dbase + dl;
  float An[4];
#pragma unroll
  for (int i = 0; i < 4; ++i) An[i] = -__expf(A_log[d * 16 + g * 4 + i]);
  const float bdt = b_dt[d];
  const float Dpd = (PASS == 1) ? Dp[d] : 0.f;
  const size_t chainbase = ((size_t)(b * NC + ch) * DINNER + d) * 16 + g * 4;
  float s0 = 0.f, s1 = 0.f, s2 = 0.f, s3 = 0.f;
  float sumdelta = 0.f;
  if (PASS == 1) {
    const float4 si = *(const float4*)(s_init + chainbase);
    s0 = si.x; s1 = si.y; s2 = si.z; s3 = si.w;
  }
  const int tb = b * LSEQ + ch * LC;

  auto stage = [&](int buf, int tile) {
    const int t0 = tb + tile * 16;
    float* sm = smem[buf];
    {
      int r = tid >> 4, w = tid & 15;
      gload16(delta_pre + (size_t)(t0 + r) * 2048 + dbase + w * 4, sm + 0    + wave * 256);
      gload16(u         + (size_t)(t0 + r) * 2048 + dbase + w * 4, sm + 1024 + wave * 256);
      if (PASS == 1)
        gload16(xz + (size_t)(t0 + r) * 4096 + 2048 + dbase + w * 4, sm + 2048 + wave * 256);
    }
    if (wave < 2) {
      int c2 = wave * 64 + (tid & 63);
      int r2 = c2 >> 3, w2 = c2 & 7;
      gload16(x_dbl + (size_t)(t0 + r2) * 128 + 64 + w2 * 4, sm + 3072 + wave * 256);
    }
  };

  stage(0, 0);
  for (int tile = 0; tile < LC / 16; ++tile) {
    __syncthreads();                      // staged tile ready; prev reads done
    if (tile + 1 < LC / 16) stage((tile + 1) & 1, tile + 1);
    const float* sm = smem[tile & 1];
#pragma unroll
    for (int r = 0; r < 16; ++r) {
      float dp = sm[r * 64 + dl];
      float ut = sm[1024 + r * 64 + dl];
      const float4 Bp = *(const float4*)(sm + 3072 + r * 32 + g * 4);
      float xs = dp + bdt;
      float delta = (xs > 15.f) ? xs : __logf(1.f + __expf(xs));   // softplus
      if (PASS == 0) sumdelta += delta;
      float dBu = delta * ut;
      float e0 = __expf(delta * An[0]); s0 = fmaf(e0, s0, dBu * Bp.x);
      float e1 = __expf(delta * An[1]); s1 = fmaf(e1, s1, dBu * Bp.y);
      float e2 = __expf(delta * An[2]); s2 = fmaf(e2, s2, dBu * Bp.z);
      float e3 = __expf(delta * An[3]); s3 = fmaf(e3, s3, dBu * Bp.w);
      if (PASS == 1) {
        const float4 Cp = *(const float4*)(sm + 3072 + r * 32 + 16 + g * 4);
        float zt = sm[2048 + r * 64 + dl];
        float y = s0 * Cp.x;
        y = fmaf(s1, Cp.y, y);
        y = fmaf(s2, Cp.z, y);
        y = fmaf(s3, Cp.w, y);
        y += __shfl_xor(y, 1);
        y += __shfl_xor(y, 2);
        if (g == 0) {
          const int t = tb + tile * 16 + r;
          float yf = (y + ut * Dpd) * (zt / (1.f + __expf(-zt)));  // + u*D, * silu(z)
          y_bf[(size_t)t * 2048 + d] = f2bf(yf);
        }
      }
    }
  }
  if (PASS == 0) {
    float4 P, S;
    P.x = __expf(An[0] * sumdelta);
    P.y = __expf(An[1] * sumdelta);
    P.z = __expf(An[2] * sumdelta);
    P.w = __expf(An[3] * sumdelta);
    S.x = s0; S.y = s1; S.z = s2; S.w = s3;
    *(float4*)(Pc + chainbase) = P;
    *(float4*)(Sc + chainbase) = S;
  }
}

// sequential composition over the NC chunk summaries, one thread per chain
__global__ __launch_bounds__(256) void scan_mid_kernel(const float* __restrict__ Pc,
                                                       const float* __restrict__ Sc,
                                                       float* __restrict__ s_init) {
  int i = blockIdx.x * 256 + threadIdx.x;   // 65536 chains: (b*DINNER+d)*16+n
  int b = i >> 15;
  int rest = i & 32767;
  const size_t stride = (size_t)DINNER * 16;
  size_t base = (size_t)b * NC * stride + rest;
  float s = 0.f;
#pragma unroll
  for (int c = 0; c < NC; ++c) {
    s_init[base + c * stride] = s;
    s = fmaf(Pc[base + c * stride], s, Sc[base + c * stride]);
  }
}

// ---------------- launch ----------------
extern "C" void kernel_launch(void* const* d_in, const int* in_sizes, int n_in,
                              void* d_out, int out_size, void* d_ws, size_t ws_size,
                              hipStream_t stream) {
  (void)in_sizes; (void)n_in; (void)out_size; (void)ws_size;
  const float* x      = (const float*)d_in[0];
  const float* W_in   = (const float*)d_in[1];
  const float* conv_w = (const float*)d_in[2];
  const float* conv_b = (const float*)d_in[3];
  const float* W_x    = (const float*)d_in[4];
  const float* W_dt   = (const float*)d_in[5];
  const float* b_dt   = (const float*)d_in[6];
  const float* A_log  = (const float*)d_in[7];
  const float* Dp     = (const float*)d_in[8];
  const float* W_out  = (const float*)d_in[9];
  float* out = (float*)d_out;

  char* ws = (char*)d_ws;
  size_t off = 0;
  auto alloc = [&](size_t bytes) { void* p = ws + off; off += (bytes + 255) & ~(size_t)255; return p; };
  unsigned short* x_bf    = (unsigned short*)alloc((size_t)N_X * 2);
  unsigned short* Win_bf  = (unsigned short*)alloc((size_t)N_WIN * 2);
  unsigned short* Wout_bf = (unsigned short*)alloc((size_t)N_WOUT * 2);
  unsigned short* Wx_bf   = (unsigned short*)alloc((size_t)N_WXP * 2);
  unsigned short* Wdt_bf  = (unsigned short*)alloc((size_t)N_WDT * 2);
  float* xz        = (float*)alloc((size_t)TTOT * 4096 * 4);
  float* u         = (float*)alloc((size_t)TTOT * 2048 * 4);
  unsigned short* u_bf = (unsigned short*)alloc((size_t)TTOT * 2048 * 2);
  float* x_dbl     = (float*)alloc((size_t)TTOT * 128 * 4);
  unsigned short* dt_bf = (unsigned short*)alloc((size_t)TTOT * 64 * 2);
  float* delta_pre = (float*)alloc((size_t)TTOT * 2048 * 4);
  unsigned short* y_bf  = (unsigned short*)alloc((size_t)TTOT * 2048 * 2);
  float* Pc     = (float*)alloc((size_t)BATCH * NC * DINNER * 16 * 4);
  float* Sc     = (float*)alloc((size_t)BATCH * NC * DINNER * 16 * 4);
  float* s_init = (float*)alloc((size_t)BATCH * NC * DINNER * 16 * 4);
  float* xdbl_part = (float*)alloc((size_t)KSPLIT * 2048 * 128 * 4);

  // all f32->bf16 casts in one launch
  cast_all_kernel<<<CAST_TOT / 1024, 256, 0, stream>>>(x, W_in, W_out, W_dt, W_x,
                                                       x_bf, Win_bf, Wout_bf, Wdt_bf, Wx_bf);

  // in_proj: xz = x @ W_in^T   (2048 x 4096, K=1024)
  gemm_bt<<<dim3(32, 16, 1), 256, 0, stream>>>(x_bf, 1024, Win_bf, 1024, xz, 4096, 1024, 0, 0);
  // conv + silu -> u (f32 + bf16)
  conv_silu_kernel<<<(TTOT * DINNER) / 256, 256, 0, stream>>>(xz, conv_w, conv_b, u, u_bf);
  // x_dbl = u @ W_x^T  (2048 x 128(pad), K=2048), split-K over 8 slices of 256
  gemm_bt<<<dim3(1, 16, KSPLIT), 256, 0, stream>>>(u_bf, 2048, Wx_bf, 2048, xdbl_part, 128,
                                                   2048 / KSPLIT, 2048 / KSPLIT,
                                                   (size_t)2048 * 128);
  reduce_xdbl_kernel<<<(2048 * 128) / 256, 256, 0, stream>>>(xdbl_part, x_dbl, dt_bf);
  // delta_pre = dt @ W_dt^T  (2048 x 2048, K=64)
  gemm_bt<<<dim3(16, 16, 1), 256, 0, stream>>>(dt_bf, 64, Wdt_bf, 64, delta_pre, 2048, 64, 0, 0);
  // chunked selective scan
  scan_pass_kernel<0><<<dim3(DINNER / 64, NC, BATCH), 256, 0, stream>>>(
      delta_pre, b_dt, u, xz, x_dbl, A_log, Dp, Pc, Sc, nullptr, nullptr);
  scan_mid_kernel<<<(BATCH * DINNER * 16) / 256, 256, 0, stream>>>(Pc, Sc, s_init);
  scan_pass_kernel<1><<<dim3(DINNER / 64, NC, BATCH), 256, 0, stream>>>(
      delta_pre, b_dt, u, xz, x_dbl, A_log, Dp, nullptr, nullptr, s_init, y_bf);
  // out = y @ W_out^T  (2048 x 1024, K=2048)
  gemm_bt<<<dim3(8, 16, 1), 256, 0, stream>>>(y_bf, 2048, Wout_bf, 2048, out, 1024, 2048, 0, 0);
}